// Round 1
// baseline (86.716 us; speedup 1.0000x reference)
//
#include <hip/hip_runtime.h>

#define RSIZE 32
#define NB 64
#define NP 256
#define NSEG 255
#define RWIDTH 0.5f
#define REPS 1e-6f
#define RTINY 1e-12f
#define CHUNKS 4
#define TPB 256

__global__ __launch_bounds__(TPB) void raster_kernel(
    const float* __restrict__ points,
    const float* __restrict__ atts,
    float* __restrict__ out)
{
    __shared__ float sx[NP];
    __shared__ float sy[NP];
    __shared__ float spen[NP];
    __shared__ float sa[NP];
    __shared__ float4 seg4[NSEG * 4];
    __shared__ float wsx[4], wsy[4];

    const int b = blockIdx.x >> 2;        // / CHUNKS
    const int chunk = blockIdx.x & 3;
    const int tid = threadIdx.x;
    const int lane = tid & 63;
    const int wave = tid >> 6;

    // ---- load inputs (coalesced float2) ----
    float2 pt = ((const float2*)points)[b * NP + tid];
    float2 at = ((const float2*)atts)[b * NP + tid];
    spen[tid] = at.x;      // pen
    sa[tid]   = at.y;      // intensity

    // ---- inclusive scan: px from points[...,1], py from points[...,0] ----
    float ax = pt.y;
    float ay = pt.x;
    for (int off = 1; off < 64; off <<= 1) {
        float tx = __shfl_up(ax, off, 64);
        float ty = __shfl_up(ay, off, 64);
        if (lane >= off) { ax += tx; ay += ty; }
    }
    if (lane == 63) { wsx[wave] = ax; wsy[wave] = ay; }
    __syncthreads();
    float ox = 0.f, oy = 0.f;
    #pragma unroll
    for (int w = 0; w < 3; ++w) {
        if (w < wave) { ox += wsx[w]; oy += wsy[w]; }
    }
    // SIZE=32 is a power of two: multiply-after-scan is exact either way
    sx[tid] = (ax + ox) * (float)RSIZE;
    sy[tid] = (ay + oy) * (float)RSIZE;
    __syncthreads();

    // ---- per-segment constants into LDS ----
    if (tid < NSEG) {
        float p0x = sx[tid],     p0y = sy[tid];
        float p1x = sx[tid + 1], p1y = sy[tid + 1];
        bool cm  = ((p1x != 0.f) && (p1y != 0.f)) || ((p0x != 0.f) && (p0y != 0.f));
        bool act = cm && (spen[tid + 1] == 0.f);
        // cx/cy union-of-intervals == simple min/max bbox (second interval is a subset)
        float lox = fminf(p0x, p1x) - RWIDTH;
        float hix = fmaxf(p0x, p1x) + RWIDTH;
        float loy = fminf(p0y, p1y) - RWIDTH;
        float hiy = fmaxf(p0y, p1y) + RWIDTH;
        if (!act) lox = 3.0e38f;  // bbox can never pass
        float d1 = p1x - p0x, d2 = p1y - p0y;
        float c  = p1y * p0x - p1x * p0y;
        float inv = 1.0f / (sqrtf(d1 * d1 + d2 * d2 + RTINY) + REPS);
        float pr0 = (d1 == 0.f) ? 1.f : 0.f;
        float pr1 = (d2 == 0.f) ? 1.f : 0.f;
        seg4[tid * 4 + 0] = make_float4(lox, hix, loy, hiy);
        seg4[tid * 4 + 1] = make_float4(p0x, p0y, d1, d2);
        seg4[tid * 4 + 2] = make_float4(c, inv, sa[tid], sa[tid + 1]);
        seg4[tid * 4 + 3] = make_float4(pr0, pr1, 0.f, 0.f);
    }
    __syncthreads();

    // ---- rasterize: one thread per pixel, loop segments ----
    const int pix = chunk * TPB + tid;          // 0..1023 within batch
    const float fx = (float)(pix >> 5);         // ii (row)   == ix
    const float fy = (float)(pix & 31);         // jj (col)   == iy
    float vmax = 0.f;

    #pragma unroll 4
    for (int i = 0; i < NSEG; ++i) {
        float4 bb = seg4[i * 4 + 0];            // LDS broadcast (uniform addr)
        bool inbox = (fx >= bb.x) & (fx <= bb.y) & (fy >= bb.z) & (fy <= bb.w);
        if (inbox) {
            float4 q0 = seg4[i * 4 + 1];        // p0x,p0y,d1,d2
            float4 q1 = seg4[i * 4 + 2];        // c,inv,a0,a1
            float4 q2 = seg4[i * 4 + 3];        // pred0,pred1
            float val  = fabsf(q0.z * fy - q0.w * fx + q1.x) * q1.y;
            float val0 = fabsf(fx - q0.x);
            float val1 = fabsf(fy - q0.y);
            float dist = q2.x * val0 + q2.y * val1 + (1.f - q2.x - q2.y) * val;
            if (dist < RWIDTH) {
                float dx0 = fx - q0.x, dy0 = fy - q0.y;
                float p1x = q0.x + q0.z, p1y = q0.y + q0.w;
                float dx1 = fx - p1x, dy1 = fy - p1y;
                float dd = dist * dist;
                float z0 = dx0 * dx0 + dy0 * dy0 + RTINY - dd;
                float z1 = dx1 * dx1 + dy1 * dy1 + RTINY - dd;
                float l0 = (z0 > 0.f) ? sqrtf(fmaxf(z0, RTINY)) : 0.f;
                float l1 = (z1 > 0.f) ? sqrtf(fmaxf(z1, RTINY)) : 0.f;
                float v = (l0 * q1.z + l1 * q1.w) / (l0 + l1 + REPS);
                vmax = fmaxf(vmax, v);
            }
        }
    }
    out[b * (RSIZE * RSIZE) + pix] = fminf(1.f, vmax) * 2.f - 1.f;
}

extern "C" void kernel_launch(void* const* d_in, const int* in_sizes, int n_in,
                              void* d_out, int out_size, void* d_ws, size_t ws_size,
                              hipStream_t stream) {
    const float* points = (const float*)d_in[0];
    const float* atts   = (const float*)d_in[1];
    float* out = (float*)d_out;
    raster_kernel<<<NB * CHUNKS, TPB, 0, stream>>>(points, atts, out);
}

// Round 2
// 70.992 us; speedup vs baseline: 1.2215x; 1.2215x over previous
//
#include <hip/hip_runtime.h>

#define RSIZE 32
#define NB 64
#define NP 256
#define NSEG 255
#define RWIDTH 0.5f
#define REPS 1e-6f
#define RTINY 1e-12f
#define CHUNKS 4
#define TPB 256
#define RPC 8              // rows (of 32) covered per block: 256 px / 32 cols
#define LCAP 256           // per-row candidate list capacity (>= NSEG, can't overflow)

__global__ __launch_bounds__(TPB) void raster_kernel(
    const float* __restrict__ points,
    const float* __restrict__ atts,
    float* __restrict__ out)
{
    __shared__ float sx[NP];
    __shared__ float sy[NP];
    __shared__ float spen[NP];
    __shared__ float sa[NP];
    __shared__ float4 seg4[(NSEG + 1) * 4];     // entry 255 = sentinel (never passes)
    __shared__ float wsx[4], wsy[4];
    __shared__ int   counts[RPC];
    __shared__ unsigned char lists[RPC][LCAP];  // segment indices per local row

    const int b     = blockIdx.x >> 2;          // / CHUNKS
    const int chunk = blockIdx.x & 3;
    const int tid   = threadIdx.x;
    const int lane  = tid & 63;
    const int wave  = tid >> 6;
    const int rbase = chunk * RPC;              // first global row of this chunk

    // ---- load inputs (coalesced float2) ----
    float2 pt = ((const float2*)points)[b * NP + tid];
    float2 at = ((const float2*)atts)[b * NP + tid];
    spen[tid] = at.x;      // pen
    sa[tid]   = at.y;      // intensity

    // ---- init candidate lists to 0xFF (sentinel idx 255) + counters + sentinel seg ----
    ((unsigned int*)lists)[tid * 2 + 0] = 0xFFFFFFFFu;
    ((unsigned int*)lists)[tid * 2 + 1] = 0xFFFFFFFFu;
    if (tid < RPC) counts[tid] = 0;
    if (tid == NSEG) seg4[NSEG * 4 + 0] = make_float4(3.0e38f, -3.0e38f, 3.0e38f, -3.0e38f);

    // ---- inclusive scan: px from points[...,1], py from points[...,0] ----
    float ax = pt.y;
    float ay = pt.x;
    for (int off = 1; off < 64; off <<= 1) {
        float tx = __shfl_up(ax, off, 64);
        float ty = __shfl_up(ay, off, 64);
        if (lane >= off) { ax += tx; ay += ty; }
    }
    if (lane == 63) { wsx[wave] = ax; wsy[wave] = ay; }
    __syncthreads();
    float ox = 0.f, oy = 0.f;
    #pragma unroll
    for (int w = 0; w < 3; ++w) {
        if (w < wave) { ox += wsx[w]; oy += wsy[w]; }
    }
    sx[tid] = (ax + ox) * (float)RSIZE;
    sy[tid] = (ay + oy) * (float)RSIZE;
    __syncthreads();

    // ---- per-segment constants + row-binning (fused: only own registers needed) ----
    if (tid < NSEG) {
        float p0x = sx[tid],     p0y = sy[tid];
        float p1x = sx[tid + 1], p1y = sy[tid + 1];
        bool cm  = ((p1x != 0.f) && (p1y != 0.f)) || ((p0x != 0.f) && (p0y != 0.f));
        bool act = cm && (spen[tid + 1] == 0.f);
        // cx/cy union-of-intervals == simple min/max bbox (second interval is a subset)
        float lox = fminf(p0x, p1x) - RWIDTH;
        float hix = fmaxf(p0x, p1x) + RWIDTH;
        float loy = fminf(p0y, p1y) - RWIDTH;
        float hiy = fmaxf(p0y, p1y) + RWIDTH;
        float d1 = p1x - p0x, d2 = p1y - p0y;
        float c  = p1y * p0x - p1x * p0y;
        float inv = 1.0f / (sqrtf(d1 * d1 + d2 * d2 + RTINY) + REPS);
        float pr0 = (d1 == 0.f) ? 1.f : 0.f;
        float pr1 = (d2 == 0.f) ? 1.f : 0.f;
        seg4[tid * 4 + 0] = make_float4(lox, hix, loy, hiy);
        seg4[tid * 4 + 1] = make_float4(p0x, p0y, d1, d2);
        seg4[tid * 4 + 2] = make_float4(c, inv, sa[tid], sa[tid + 1]);
        seg4[tid * 4 + 3] = make_float4(pr0, pr1, 0.f, 0.f);
        if (act) {
            // rows r with r >= lox && r <= hix, clipped to this chunk
            int r0 = max(rbase,           (int)ceilf(lox));
            int r1 = min(rbase + RPC - 1, (int)floorf(hix));
            for (int r = r0; r <= r1; ++r) {
                int pos = atomicAdd(&counts[r - rbase], 1);
                lists[r - rbase][pos] = (unsigned char)tid;
            }
        }
    }
    __syncthreads();

    // ---- rasterize: one thread per pixel, loop row's candidate list ----
    const int pix  = chunk * TPB + tid;         // 0..1023 within batch
    const int rowl = (pix >> 5) & (RPC - 1);    // local row
    const float fx = (float)(pix >> 5);         // ii (row) == ix
    const float fy = (float)(pix & 31);         // jj (col) == iy
    const unsigned int* lst = (const unsigned int*)lists[rowl];
    const int n = counts[rowl];
    float vmax = 0.f;

    for (int j4 = 0; j4 < n; j4 += 4) {
        unsigned int pk = lst[j4 >> 2];         // 4 candidate indices (tail = 0xFF sentinel)
        #pragma unroll
        for (int k = 0; k < 4; ++k) {
            int i = (pk >> (8 * k)) & 255;
            float4 bb = seg4[i * 4 + 0];
            // x-range guaranteed by binning; only y-range to test
            if (fy >= bb.z && fy <= bb.w) {
                float4 q0 = seg4[i * 4 + 1];    // p0x,p0y,d1,d2
                float4 q1 = seg4[i * 4 + 2];    // c,inv,a0,a1
                float4 q2 = seg4[i * 4 + 3];    // pred0,pred1
                float val  = fabsf(q0.z * fy - q0.w * fx + q1.x) * q1.y;
                float val0 = fabsf(fx - q0.x);
                float val1 = fabsf(fy - q0.y);
                float dist = q2.x * val0 + q2.y * val1 + (1.f - q2.x - q2.y) * val;
                if (dist < RWIDTH) {
                    float dx0 = fx - q0.x, dy0 = fy - q0.y;
                    float p1x = q0.x + q0.z, p1y = q0.y + q0.w;
                    float dx1 = fx - p1x, dy1 = fy - p1y;
                    float dd = dist * dist;
                    float z0 = dx0 * dx0 + dy0 * dy0 + RTINY - dd;
                    float z1 = dx1 * dx1 + dy1 * dy1 + RTINY - dd;
                    float l0 = (z0 > 0.f) ? sqrtf(fmaxf(z0, RTINY)) : 0.f;
                    float l1 = (z1 > 0.f) ? sqrtf(fmaxf(z1, RTINY)) : 0.f;
                    float v = (l0 * q1.z + l1 * q1.w) / (l0 + l1 + REPS);
                    vmax = fmaxf(vmax, v);
                }
            }
        }
    }
    out[b * (RSIZE * RSIZE) + pix] = fminf(1.f, vmax) * 2.f - 1.f;
}

extern "C" void kernel_launch(void* const* d_in, const int* in_sizes, int n_in,
                              void* d_out, int out_size, void* d_ws, size_t ws_size,
                              hipStream_t stream) {
    const float* points = (const float*)d_in[0];
    const float* atts   = (const float*)d_in[1];
    float* out = (float*)d_out;
    raster_kernel<<<NB * CHUNKS, TPB, 0, stream>>>(points, atts, out);
}